// Round 3
// baseline (1378.256 us; speedup 1.0000x reference)
//
#include <hip/hip_runtime.h>
#include <hip/hip_bf16.h>
#include <math.h>

constexpr int BB = 256;
constexpr int NCLS = 10;
constexpr int NROUTE = 1152;

typedef __attribute__((ext_vector_type(8))) short s16x8;
typedef __attribute__((ext_vector_type(4))) float f32x4;

__device__ __forceinline__ void gl16(const void* g, void* l) {
  __builtin_amdgcn_global_load_lds(
      (const __attribute__((address_space(1))) void*)g,
      (__attribute__((address_space(3))) void*)l, 16, 0, 0);
}

// ---- conv1: x[256,1,28,28] -> hT[b_l][y*20+x][oc] bf16 hi/lo (NHWC), relu ----
__global__ __launch_bounds__(256) void k_conv1b(const float* __restrict__ x,
    const float* __restrict__ w, const float* __restrict__ bias,
    __hip_bfloat16* __restrict__ hT_hi, __hip_bfloat16* __restrict__ hT_lo,
    int b0) {
  int b_l = blockIdx.x >> 2, q = blockIdx.x & 3;
  __shared__ float sx[784];
  __shared__ float sw[64 * 81];
  int t = threadIdx.x;
  for (int i = t; i < 784; i += 256) sx[i] = x[(size_t)(b0 + b_l) * 784 + i];
  for (int i = t; i < 5184; i += 256) sw[i] = w[(size_t)q * 5184 + i];
  __syncthreads();
  int oc = q * 64 + (t & 63);
  int wv = t >> 6;
  float wreg[81];
#pragma unroll
  for (int k = 0; k < 81; ++k) wreg[k] = sw[(t & 63) * 81 + k];
  float bv = bias[oc];
  for (int st = wv * 10; st < wv * 10 + 10; ++st) {
    int y = st >> 1, x0 = (st & 1) * 10;
    float acc[10];
#pragma unroll
    for (int i = 0; i < 10; ++i) acc[i] = bv;
#pragma unroll
    for (int ky = 0; ky < 9; ++ky) {
      const float* row = &sx[(y + ky) * 28 + x0];
      float rv[18];
#pragma unroll
      for (int i = 0; i < 18; ++i) rv[i] = row[i];
#pragma unroll
      for (int kx = 0; kx < 9; ++kx) {
        float wgt = wreg[ky * 9 + kx];
#pragma unroll
        for (int xi = 0; xi < 10; ++xi) acc[xi] = fmaf(rv[kx + xi], wgt, acc[xi]);
      }
    }
#pragma unroll
    for (int xi = 0; xi < 10; ++xi) {
      float av = fmaxf(acc[xi], 0.f);
      __hip_bfloat16 hi = __float2bfloat16(av);
      float lo = av - __bfloat162float(hi);
      size_t idx = ((size_t)(b_l * 400 + y * 20 + x0 + xi)) * 256 + oc;
      hT_hi[idx] = hi;
      hT_lo[idx] = __float2bfloat16(lo);
    }
  }
}

// ---- weight convert: prim_w[oc][ic][81] f32 -> wt[tap(84)][oc][ic] bf16 hi/lo ----
// blocks 1024..1215 zero the 3 dummy taps (81..83)
__global__ __launch_bounds__(256) void k_cvtw(const float* __restrict__ w,
    __hip_bfloat16* __restrict__ wt_hi, __hip_bfloat16* __restrict__ wt_lo) {
  int bid = blockIdx.x;
  int t = threadIdx.x;
  if (bid >= 1024) {
    int idx = (bid - 1024) * 1024 + t * 4;
    size_t base = (size_t)81 * 65536 + idx;
#pragma unroll
    for (int k = 0; k < 4; ++k) {
      wt_hi[base + k] = __float2bfloat16(0.f);
      wt_lo[base + k] = __float2bfloat16(0.f);
    }
    return;
  }
  int oc = bid >> 2, icq = bid & 3;
  __shared__ float sw[5184];
  const float* src = w + ((size_t)oc * 256 + icq * 64) * 81;
  for (int i = t; i < 5184; i += 256) sw[i] = src[i];
  __syncthreads();
  for (int i = t; i < 5184; i += 256) {
    int tap = i >> 6, icl = i & 63;
    float v = sw[icl * 81 + tap];
    __hip_bfloat16 hi = __float2bfloat16(v);
    float lo = v - __bfloat162float(hi);
    size_t dst = (size_t)tap * 65536 + (size_t)oc * 256 + icq * 64 + icl;
    wt_hi[dst] = hi;
    wt_lo[dst] = __float2bfloat16(lo);
  }
}

// ---- primary caps conv: plane-cached implicit GEMM, bf16 MFMA, 3-product hi/lo ----
// Block: M=160 (4 batches x 40 padded spatial), N=64 oc, all 256 ic, all 81(+3) taps.
// LDS: A dbuf 2x51200 (4b x 400px x 8ic, hi+lo, pixel-XOR-swizzled)
//      B dbuf 2x8192  (64oc x [4taps x 8ic], bit[6:4]-XOR-swizzled)
// K-step = 4 taps x 8 ic = 32. 32 ic-chunks x 21 quads = 672 steps.
constexpr int A_LO = 25600;
constexpr int A_BUFSZ = 51200;
constexpr int B_BASE = 102400;
constexpr int B_BUFSZ = 8192;

__global__ __launch_bounds__(256, 1) void k_prim2(
    const __hip_bfloat16* __restrict__ hT_hi, const __hip_bfloat16* __restrict__ hT_lo,
    const __hip_bfloat16* __restrict__ wt_hi, const __hip_bfloat16* __restrict__ wt_lo,
    float* __restrict__ pout, int b0) {
  __shared__ __align__(16) char lds[118784];
  int bid = blockIdx.x;
  int Nblk = bid & 3, Mblk = bid >> 2;
  int oc0 = Nblk * 64;
  int lb4 = Mblk * 4;  // local batch base into hT
  int tid = threadIdx.x, wv = tid >> 6, lane = tid & 63;
  int slot = lane >> 4, lr = lane & 15;
  int wr = wv >> 1, wc = wv & 1;

  int baseA[5], pb[5], oyb[5];
#pragma unroll
  for (int i = 0; i < 5; ++i) {
    int row = wr * 80 + i * 16 + lr;
    int bl = row / 40;
    int s = row - bl * 40; if (s > 35) s = 35;
    int oy = s / 6, ox = s - oy * 6;
    baseA[i] = bl * 6400;
    pb[i] = (2 * oy) * 20 + 2 * ox;
    oyb[i] = oy & 1;
  }
  int uu[2];
#pragma unroll
  for (int j = 0; j < 2; ++j) {
    int n = wc * 32 + j * 16 + lr;
    int u = n * 64 + slot * 16;
    uu[j] = u ^ (((u >> 7) & 7) << 4);
  }
  const char* hTh = (const char*)hT_hi;
  const char* hTl = (const char*)hT_lo;
  const char* wth = (const char*)wt_hi;
  const char* wtl = (const char*)wt_lo;

  // stage one 16B-slice group of A (chunk ic0=icn) into A-buf ab
  auto stageA = [&](int ab, int icn, int kk, bool lo) {
    int L = kk * 256 + tid;
    if (L < 1600) {
      int b = L / 400;
      int pa = L - b * 400;
      int pe = pa ^ ((pa / 40) & 1);  // involution: element for linear dest
      size_t so = ((size_t)((lb4 + b) * 400 + pe)) * 512 + (size_t)icn * 2;
      const char* src = lo ? hTl : hTh;
      char* dst = lds + ab * A_BUFSZ + (lo ? A_LO : 0) + kk * 4096 + wv * 1024;
      gl16(src + so, dst);
    }
  };
  // stage B for (quad qq, chunk icn) into B-buf bb  (2 gl16/thread)
  auto stageB = [&](int bb, int icn, int qq) {
    int a = tid * 16;
    int e = a ^ (((a >> 7) & 7) << 4);
    int oce = e >> 6, jq = (e >> 4) & 3;
    size_t so = ((size_t)(qq * 4 + jq) * 65536 + (size_t)(oc0 + oce) * 256 + (size_t)icn) * 2;
    char* dh = lds + B_BASE + bb * B_BUFSZ + wv * 1024;
    gl16(wth + so, dh);
    gl16(wtl + so, dh + 4096);
  };

  f32x4 acc[5][2];
#pragma unroll
  for (int i = 0; i < 5; ++i)
#pragma unroll
    for (int j = 0; j < 2; ++j) acc[i][j] = (f32x4){0.f, 0.f, 0.f, 0.f};

  // prologue: A chunk0 -> buf0, B (c0,q0) -> buf0
#pragma unroll
  for (int kk = 0; kk < 7; ++kk) { stageA(0, 0, kk, false); stageA(0, 0, kk, true); }
  stageB(0, 0, 0);
  __syncthreads();

  int step = 0;
#pragma unroll 1
  for (int c = 0; c < 32; ++c) {
    int ab = c & 1;
#pragma unroll 1
    for (int q = 0; q < 21; ++q, ++step) {
      // prefetch next B
      int nq = q + 1, nc = c;
      if (nq == 21) { nq = 0; nc = c + 1; }
      if (nc < 32) stageB((step + 1) & 1, nc * 8, nq);
      // prefetch next A chunk, spread over quads 1..14
      if (c < 31 && q >= 1 && q <= 14) {
        stageA(ab ^ 1, (c + 1) * 8, (q - 1) >> 1, (q & 1) == 0);
      }
      // this lane's tap
      int tap = q * 4 + slot;
      int tp = tap > 80 ? 80 : tap;
      int ky = tp / 9, kx = tp - ky * 9;
      int d20 = ky * 20 + kx;
      int kyh = (ky >> 1) & 1;
      const char* Ab = lds + ab * A_BUFSZ;
      const char* Bb = lds + B_BASE + (step & 1) * B_BUFSZ;
      s16x8 ah[5], al[5], bh[2], bl[2];
#pragma unroll
      for (int j = 0; j < 2; ++j) {
        bh[j] = *(const s16x8*)(Bb + uu[j]);
        bl[j] = *(const s16x8*)(Bb + 4096 + uu[j]);
      }
#pragma unroll
      for (int i = 0; i < 5; ++i) {
        int p = pb[i] + d20;
        int pp = p ^ (oyb[i] ^ kyh);
        int ao = baseA[i] + (pp << 4);
        ah[i] = *(const s16x8*)(Ab + ao);
        al[i] = *(const s16x8*)(Ab + A_LO + ao);
      }
#pragma unroll
      for (int i = 0; i < 5; ++i)
#pragma unroll
        for (int j = 0; j < 2; ++j) {
          acc[i][j] = __builtin_amdgcn_mfma_f32_16x16x32_bf16(ah[i], bh[j], acc[i][j], 0, 0, 0);
          acc[i][j] = __builtin_amdgcn_mfma_f32_16x16x32_bf16(ah[i], bl[j], acc[i][j], 0, 0, 0);
          acc[i][j] = __builtin_amdgcn_mfma_f32_16x16x32_bf16(al[i], bh[j], acc[i][j], 0, 0, 0);
        }
      __syncthreads();
    }
  }
  // store
#pragma unroll
  for (int i = 0; i < 5; ++i) {
    int rowb = wr * 80 + i * 16 + slot * 4;
#pragma unroll
    for (int rg = 0; rg < 4; ++rg) {
      int r = rowb + rg;
      int bl_ = r / 40, s = r - bl_ * 40;
      if (s < 36) {
        int gm = (b0 + lb4 + bl_) * 36 + s;
#pragma unroll
        for (int j = 0; j < 2; ++j) {
          int col = oc0 + wc * 32 + j * 16 + lr;
          pout[(size_t)gm * 256 + col] = acc[i][j][rg];
        }
      }
    }
  }
}

// ---- squash: pout + bias -> psT[b][i*1152 + r] ----
__global__ __launch_bounds__(256) void k_squash2(const float* __restrict__ pout,
    const float* __restrict__ bias, float* __restrict__ psT) {
  int b = blockIdx.x;
  int t = threadIdx.x;
  __shared__ float buf[9216];
  __shared__ float sq[256];
  __shared__ float sc[32];
  float bv = bias[t];
  for (int s = 0; s < 36; ++s) {
    size_t base = ((size_t)(b * 36 + s)) * 256 + t;
    float val = pout[base] + bv;
    sq[t] = val * val;
    __syncthreads();
    if (t < 32) {
      float ss = 0.f;
#pragma unroll
      for (int i = 0; i < 8; ++i) ss += sq[t + i * 32];
      sc[t] = sqrtf(ss) / (1.f + ss);
    }
    __syncthreads();
    buf[t * 36 + s] = val * sc[t & 31];
    __syncthreads();
  }
  float* dst = psT + (size_t)b * 9216;
  for (int i = t; i < 9216; i += 256) dst[i] = buf[i];
}

// ---- fused routing: block = (class c, batch pair); rw read once per pair ----
__global__ __launch_bounds__(256) void k_route2(const float* __restrict__ psT,
    const float* __restrict__ rw, float* __restrict__ vout) {
  int c = blockIdx.x / 128;
  int bp0 = (blockIdx.x - c * 128) * 2;
  __shared__ float pri[2][16][NROUTE];
  __shared__ float wred[4];
  __shared__ float red[64];
  __shared__ float vsq[2][16];
  __shared__ float sca[2];
  int tid = threadIdx.x, wv = tid >> 6;

  for (int r = tid; r < NROUTE; r += 256) {
    float p8a[8], p8b[8];
#pragma unroll
    for (int i = 0; i < 8; ++i) {
      p8a[i] = psT[(size_t)bp0 * 9216 + i * 1152 + r];
      p8b[i] = psT[(size_t)(bp0 + 1) * 9216 + i * 1152 + r];
    }
    const float4* wp4 = (const float4*)&rw[((size_t)c * NROUTE + r) * 128];
    float pra[16], prb[16];
#pragma unroll
    for (int o = 0; o < 16; ++o) { pra[o] = 0.f; prb[o] = 0.f; }
#pragma unroll
    for (int i = 0; i < 8; ++i) {
      float av = p8a[i], bvv = p8b[i];
#pragma unroll
      for (int o4 = 0; o4 < 4; ++o4) {
        float4 w4 = wp4[i * 4 + o4];
        pra[o4 * 4 + 0] += av * w4.x; prb[o4 * 4 + 0] += bvv * w4.x;
        pra[o4 * 4 + 1] += av * w4.y; prb[o4 * 4 + 1] += bvv * w4.y;
        pra[o4 * 4 + 2] += av * w4.z; prb[o4 * 4 + 2] += bvv * w4.z;
        pra[o4 * 4 + 3] += av * w4.w; prb[o4 * 4 + 3] += bvv * w4.w;
      }
    }
#pragma unroll
    for (int o = 0; o < 16; ++o) {
      pri[0][o][r] = pra[o];
      pri[1][o][r] = prb[o];
    }
  }
  float lgr[2][5];
#pragma unroll
  for (int h = 0; h < 2; ++h)
#pragma unroll
    for (int k = 0; k < 5; ++k) lgr[h][k] = 0.f;
  __syncthreads();

  for (int it = 0; it < 3; ++it) {
    for (int h = 0; h < 2; ++h) {
      float mx = -1e30f;
#pragma unroll
      for (int k = 0; k < 5; ++k) { int r = tid + k * 256; if (r < NROUTE) mx = fmaxf(mx, lgr[h][k]); }
#pragma unroll
      for (int off = 32; off; off >>= 1) mx = fmaxf(mx, __shfl_xor(mx, off));
      __syncthreads();
      if ((tid & 63) == 0) wred[wv] = mx;
      __syncthreads();
      mx = fmaxf(fmaxf(wred[0], wred[1]), fmaxf(wred[2], wred[3]));
      float er[5];
      float sm = 0.f;
#pragma unroll
      for (int k = 0; k < 5; ++k) {
        int r = tid + k * 256;
        er[k] = (r < NROUTE) ? expf(lgr[h][k] - mx) : 0.f;
        sm += er[k];
      }
#pragma unroll
      for (int off = 32; off; off >>= 1) sm += __shfl_xor(sm, off);
      __syncthreads();
      if ((tid & 63) == 0) wred[wv] = sm;
      __syncthreads();
      float inv = 1.f / (wred[0] + wred[1] + wred[2] + wred[3]);
      float a16[16];
#pragma unroll
      for (int o = 0; o < 16; ++o) a16[o] = 0.f;
#pragma unroll
      for (int k = 0; k < 5; ++k) {
        int r = tid + k * 256;
        if (r < NROUTE) {
          float pr_ = er[k] * inv;
#pragma unroll
          for (int o = 0; o < 16; ++o) a16[o] += pr_ * pri[h][o][r];
        }
      }
#pragma unroll
      for (int o = 0; o < 16; ++o)
#pragma unroll
        for (int off = 32; off; off >>= 1) a16[o] += __shfl_xor(a16[o], off);
      __syncthreads();
      if ((tid & 63) == 0) {
#pragma unroll
        for (int o = 0; o < 16; ++o) red[wv * 16 + o] = a16[o];
      }
      __syncthreads();
      if (tid < 16) {
        float s = red[tid] + red[16 + tid] + red[32 + tid] + red[48 + tid];
        red[tid] = s;
      }
      __syncthreads();
      if (tid == 0) {
        float sqs = 0.f;
        for (int o = 0; o < 16; ++o) sqs += red[o] * red[o];
        sca[h] = sqrtf(sqs) / (1.f + sqs);
      }
      __syncthreads();
      if (tid < 16) vsq[h][tid] = red[tid] * sca[h];
      __syncthreads();
      if (it < 2) {
#pragma unroll
        for (int k = 0; k < 5; ++k) {
          int r = tid + k * 256;
          if (r < NROUTE) {
            float d = 0.f;
#pragma unroll
            for (int o = 0; o < 16; ++o) d += pri[h][o][r] * vsq[h][o];
            lgr[h][k] += d;
          }
        }
      }
      __syncthreads();
    }
  }
  if (tid < 32) {
    int h = tid >> 4, o = tid & 15;
    vout[((size_t)c * BB + (bp0 + h)) * 16 + o] = vsq[h][o];
  }
}

// ---- classes + argmax one-hot mask ----
__global__ __launch_bounds__(64) void k_cls(const float* __restrict__ v,
                                            float* __restrict__ classes,
                                            float* __restrict__ masked) {
  int b = blockIdx.x;
  int t = threadIdx.x;
  __shared__ float snrm[10];
  __shared__ int samax;
  float vv[16];
  if (t < 10) {
    float sq = 0.f;
#pragma unroll
    for (int o = 0; o < 16; ++o) {
      float xx = v[(size_t)(t * BB + b) * 16 + o];
      vv[o] = xx;
      sq += xx * xx;
    }
    snrm[t] = sqrtf(sq);
  }
  __syncthreads();
  if (t == 0) {
    int am = 0;
    float bm = snrm[0];
    for (int cc = 1; cc < 10; ++cc)
      if (snrm[cc] > bm) { bm = snrm[cc]; am = cc; }
    samax = am;
  }
  __syncthreads();
  if (t < 10) {
    float mx = snrm[0];
    for (int cc = 1; cc < 10; ++cc) mx = fmaxf(mx, snrm[cc]);
    float sm = 0.f;
    for (int cc = 0; cc < 10; ++cc) sm += expf(snrm[cc] - mx);
    classes[b * 10 + t] = expf(snrm[t] - mx) / sm;
    float keep = (t == samax) ? 1.f : 0.f;
#pragma unroll
    for (int o = 0; o < 16; ++o)
      masked[(size_t)b * 160 + t * 16 + o] = vv[o] * keep;
  }
}

// ---- small FC GEMM ----
template <int ACT>
__global__ __launch_bounds__(256) void k_fc(const float* __restrict__ A,
                                            const float* __restrict__ W,
                                            const float* __restrict__ bias,
                                            float* __restrict__ O, int M, int N,
                                            int K) {
  int n0 = blockIdx.x * 64, m0 = blockIdx.y * 64;
  __shared__ float sa[64][17];
  __shared__ float sb[16][64];
  int tid = threadIdx.x, ty = tid >> 4, tx = tid & 15;
  float acc[4][4] = {};
  for (int k0 = 0; k0 < K; k0 += 16) {
    __syncthreads();
    for (int i = tid; i < 64 * 16; i += 256) {
      int m = i >> 4, k = i & 15;
      sa[m][k] = A[(size_t)(m0 + m) * K + k0 + k];
    }
    for (int i = tid; i < 16 * 64; i += 256) {
      int k = i >> 6, n = i & 63;
      int nn = n0 + n;
      sb[k][n] = (nn < N) ? W[(size_t)(k0 + k) * N + nn] : 0.f;
    }
    __syncthreads();
#pragma unroll
    for (int k = 0; k < 16; ++k) {
      float a0 = sa[ty * 4 + 0][k];
      float a1 = sa[ty * 4 + 1][k];
      float a2 = sa[ty * 4 + 2][k];
      float a3 = sa[ty * 4 + 3][k];
      float4 bv = *(const float4*)&sb[k][tx * 4];
      acc[0][0] += a0 * bv.x; acc[0][1] += a0 * bv.y; acc[0][2] += a0 * bv.z; acc[0][3] += a0 * bv.w;
      acc[1][0] += a1 * bv.x; acc[1][1] += a1 * bv.y; acc[1][2] += a1 * bv.z; acc[1][3] += a1 * bv.w;
      acc[2][0] += a2 * bv.x; acc[2][1] += a2 * bv.y; acc[2][2] += a2 * bv.z; acc[2][3] += a2 * bv.w;
      acc[3][0] += a3 * bv.x; acc[3][1] += a3 * bv.y; acc[3][2] += a3 * bv.z; acc[3][3] += a3 * bv.w;
    }
  }
#pragma unroll
  for (int i = 0; i < 4; ++i) {
    int m = m0 + ty * 4 + i;
#pragma unroll
    for (int j = 0; j < 4; ++j) {
      int n = n0 + tx * 4 + j;
      if (n < N) {
        float xv = acc[i][j] + bias[n];
        if (ACT == 0)
          xv = fmaxf(xv, 0.f);
        else
          xv = 1.f / (1.f + expf(-xv));
        O[(size_t)m * N + n] = xv;
      }
    }
  }
}

extern "C" void kernel_launch(void* const* d_in, const int* in_sizes, int n_in,
                              void* d_out, int out_size, void* d_ws,
                              size_t ws_size, hipStream_t stream) {
  (void)in_sizes; (void)n_in; (void)out_size;
  const float* x       = (const float*)d_in[0];
  const float* conv1_w = (const float*)d_in[1];
  const float* conv1_b = (const float*)d_in[2];
  const float* prim_w  = (const float*)d_in[3];
  const float* prim_b  = (const float*)d_in[4];
  const float* route_w = (const float*)d_in[5];
  const float* dec_w1  = (const float*)d_in[6];
  const float* dec_b1  = (const float*)d_in[7];
  const float* dec_w2  = (const float*)d_in[8];
  const float* dec_b2  = (const float*)d_in[9];
  const float* dec_w3  = (const float*)d_in[10];
  const float* dec_b3  = (const float*)d_in[11];
  float* out = (float*)d_out;

  char* wsb = (char*)d_ws;
  const size_t FULL_NEED = 136314880ULL;  // hT(104.9M) + wt(22.0M) + pout(9.4M)
  bool full = (ws_size >= FULL_NEED);

  __hip_bfloat16 *hT_hi, *hT_lo, *wt_hi, *wt_lo;
  float* pout;
  if (full) {
    hT_hi = (__hip_bfloat16*)(wsb);
    hT_lo = (__hip_bfloat16*)(wsb + 52428800);
    wt_hi = (__hip_bfloat16*)(wsb + 104857600);
    wt_lo = (__hip_bfloat16*)(wsb + 115867648);
    pout  = (float*)(wsb + 126877696);
  } else {
    hT_hi = (__hip_bfloat16*)(wsb);
    hT_lo = (__hip_bfloat16*)(wsb + 26214400);
    wt_hi = (__hip_bfloat16*)(wsb + 52428800);
    wt_lo = (__hip_bfloat16*)(wsb + 63438848);
    pout  = (float*)(wsb + 74448896);
  }
  // psT and later buffers alias the hT region (hT dead after k_prim2)
  float* psT = (float*)(wsb);                  // 9,437,184 B
  float* v   = (float*)(wsb + 9437184);        // 163,840 B
  float* mk  = (float*)(wsb + 9601024);        // 163,840 B
  float* h1  = (float*)(wsb + 9764864);        // 524,288 B
  float* h2  = (float*)(wsb + 10289152);       // 1,048,576 B

  k_cvtw<<<1216, 256, 0, stream>>>(prim_w, wt_hi, wt_lo);
  if (full) {
    k_conv1b<<<1024, 256, 0, stream>>>(x, conv1_w, conv1_b, hT_hi, hT_lo, 0);
    k_prim2<<<256, 256, 0, stream>>>(hT_hi, hT_lo, wt_hi, wt_lo, pout, 0);
  } else {
    for (int hh = 0; hh < 2; ++hh) {
      int b0 = hh * 128;
      k_conv1b<<<512, 256, 0, stream>>>(x, conv1_w, conv1_b, hT_hi, hT_lo, b0);
      k_prim2<<<128, 256, 0, stream>>>(hT_hi, hT_lo, wt_hi, wt_lo, pout, b0);
    }
  }
  k_squash2<<<256, 256, 0, stream>>>(pout, prim_b, psT);
  k_route2<<<1280, 256, 0, stream>>>(psT, route_w, v);
  k_cls<<<256, 64, 0, stream>>>(v, out, mk);
  k_fc<0><<<dim3(8, 4), 256, 0, stream>>>(mk, dec_w1, dec_b1, h1, 256, 512, 160);
  k_fc<0><<<dim3(16, 4), 256, 0, stream>>>(h1, dec_w2, dec_b2, h2, 256, 1024, 512);
  k_fc<1><<<dim3(13, 4), 256, 0, stream>>>(h2, dec_w3, dec_b3, out + 2560, 256, 784, 1024);
}

// Round 4
// 1314.819 us; speedup vs baseline: 1.0482x; 1.0482x over previous
//
#include <hip/hip_runtime.h>
#include <hip/hip_bf16.h>
#include <math.h>

constexpr int BB = 256;
constexpr int NCLS = 10;
constexpr int NROUTE = 1152;

typedef __attribute__((ext_vector_type(8))) short s16x8;
typedef __attribute__((ext_vector_type(4))) float f32x4;

__device__ __forceinline__ void gl16(const void* g, void* l) {
  __builtin_amdgcn_global_load_lds(
      (const __attribute__((address_space(1))) void*)g,
      (__attribute__((address_space(3))) void*)l, 16, 0, 0);
}

// ---- conv1: x[256,1,28,28] -> hT[b_l][y*20+x][oc] bf16 hi/lo (NHWC), relu ----
__global__ __launch_bounds__(256) void k_conv1b(const float* __restrict__ x,
    const float* __restrict__ w, const float* __restrict__ bias,
    __hip_bfloat16* __restrict__ hT_hi, __hip_bfloat16* __restrict__ hT_lo,
    int b0) {
  int b_l = blockIdx.x >> 2, q = blockIdx.x & 3;
  __shared__ float sx[784];
  __shared__ float sw[64 * 81];
  int t = threadIdx.x;
  for (int i = t; i < 784; i += 256) sx[i] = x[(size_t)(b0 + b_l) * 784 + i];
  for (int i = t; i < 5184; i += 256) sw[i] = w[(size_t)q * 5184 + i];
  __syncthreads();
  int oc = q * 64 + (t & 63);
  int wv = t >> 6;
  float wreg[81];
#pragma unroll
  for (int k = 0; k < 81; ++k) wreg[k] = sw[(t & 63) * 81 + k];
  float bv = bias[oc];
  for (int st = wv * 10; st < wv * 10 + 10; ++st) {
    int y = st >> 1, x0 = (st & 1) * 10;
    float acc[10];
#pragma unroll
    for (int i = 0; i < 10; ++i) acc[i] = bv;
#pragma unroll
    for (int ky = 0; ky < 9; ++ky) {
      const float* row = &sx[(y + ky) * 28 + x0];
      float rv[18];
#pragma unroll
      for (int i = 0; i < 18; ++i) rv[i] = row[i];
#pragma unroll
      for (int kx = 0; kx < 9; ++kx) {
        float wgt = wreg[ky * 9 + kx];
#pragma unroll
        for (int xi = 0; xi < 10; ++xi) acc[xi] = fmaf(rv[kx + xi], wgt, acc[xi]);
      }
    }
#pragma unroll
    for (int xi = 0; xi < 10; ++xi) {
      float av = fmaxf(acc[xi], 0.f);
      __hip_bfloat16 hi = __float2bfloat16(av);
      float lo = av - __bfloat162float(hi);
      size_t idx = ((size_t)(b_l * 400 + y * 20 + x0 + xi)) * 256 + oc;
      hT_hi[idx] = hi;
      hT_lo[idx] = __float2bfloat16(lo);
    }
  }
}

// ---- weight convert: prim_w[oc][ic][81] f32 -> wt[tap][oc][ic] bf16 hi/lo ----
__global__ __launch_bounds__(256) void k_cvtw(const float* __restrict__ w,
    __hip_bfloat16* __restrict__ wt_hi, __hip_bfloat16* __restrict__ wt_lo) {
  int oc = blockIdx.x >> 2, icq = blockIdx.x & 3;
  __shared__ float sw[5184];
  int t = threadIdx.x;
  const float* src = w + ((size_t)oc * 256 + icq * 64) * 81;
  for (int i = t; i < 5184; i += 256) sw[i] = src[i];
  __syncthreads();
  for (int i = t; i < 5184; i += 256) {
    int tap = i >> 6, icl = i & 63;
    float v = sw[icl * 81 + tap];
    __hip_bfloat16 hi = __float2bfloat16(v);
    float lo = v - __bfloat162float(hi);
    size_t dst = (size_t)tap * 65536 + (size_t)oc * 256 + icq * 64 + icl;
    wt_hi[dst] = hi;
    wt_lo[dst] = __float2bfloat16(lo);
  }
}

// ---- primary caps conv as implicit GEMM, bf16 MFMA, 3-product hi/lo ----
// (round-2 proven version) C[m][n=oc], K = 81 taps x 256 ic, split-K=3 over taps.
__global__ __launch_bounds__(256) void k_prim(
    const __hip_bfloat16* __restrict__ hT_hi, const __hip_bfloat16* __restrict__ hT_lo,
    const __hip_bfloat16* __restrict__ wt_hi, const __hip_bfloat16* __restrict__ wt_lo,
    float* __restrict__ pout) {
  int bid = blockIdx.x;
  int Nblk = bid & 3;
  int Mblk = (bid >> 2) % 36;
  int kb = bid / 144;
  int m0 = Mblk * 128, oc0 = Nblk * 64;
  __shared__ __align__(16) char lds[24576];  // Ah 8K | Al 8K | Bh 4K | Bl 4K
  int t = threadIdx.x, wv = t >> 6, lane = t & 63;
  int jswz = (t & 3) ^ ((t >> 2) & 3);
  int rA = t >> 2;
  size_t ro0, ro1;
  {
    int m = m0 + rA; int b = m / 36, s = m - b * 36, oy = s / 6, ox = s - oy * 6;
    ro0 = ((size_t)(b * 400 + oy * 40 + ox * 2)) * 512;
    m = m0 + rA + 64; b = m / 36; s = m - b * 36; oy = s / 6; ox = s - oy * 6;
    ro1 = ((size_t)(b * 400 + oy * 40 + ox * 2)) * 512;
  }
  const char* pAh = (const char*)hT_hi + jswz * 16;
  const char* pAl = (const char*)hT_lo + jswz * 16;
  size_t bo = ((size_t)(oc0 + rA)) * 512 + jswz * 16;
  const char* pBh = (const char*)wt_hi + bo;
  const char* pBl = (const char*)wt_lo + bo;
  char* dAh0 = lds + wv * 1024;
  char* dAh1 = lds + 4096 + wv * 1024;
  char* dAl0 = lds + 8192 + wv * 1024;
  char* dAl1 = lds + 12288 + wv * 1024;
  char* dBh  = lds + 16384 + wv * 1024;
  char* dBl  = lds + 20480 + wv * 1024;
  int wr = wv >> 1, wc = wv & 1;
  int swz16 = ((lane >> 4) ^ (lane & 3)) * 16;
  int arow[4], brow[2];
#pragma unroll
  for (int i = 0; i < 4; ++i) arow[i] = (wr * 64 + i * 16 + (lane & 15)) * 64 + swz16;
#pragma unroll
  for (int j = 0; j < 2; ++j) brow[j] = 16384 + (wc * 32 + j * 16 + (lane & 15)) * 64 + swz16;
  f32x4 acc[4][2];
#pragma unroll
  for (int i = 0; i < 4; ++i)
#pragma unroll
    for (int j = 0; j < 2; ++j) acc[i][j] = (f32x4){0.f, 0.f, 0.f, 0.f};

#pragma unroll 1
  for (int tt = 0; tt < 27; ++tt) {
    int tap = kb * 27 + tt;
    int ky = tap / 9, kx = tap - ky * 9;
    size_t offA = (size_t)(ky * 20 + kx) * 512;
    size_t offB = (size_t)tap * 131072;
#pragma unroll 1
    for (int icc = 0; icc < 8; ++icc) {
      size_t ko = (size_t)icc * 64;
      __syncthreads();
      gl16(pAh + ro0 + offA + ko, dAh0);
      gl16(pAh + ro1 + offA + ko, dAh1);
      gl16(pAl + ro0 + offA + ko, dAl0);
      gl16(pAl + ro1 + offA + ko, dAl1);
      gl16(pBh + offB + ko, dBh);
      gl16(pBl + offB + ko, dBl);
      __syncthreads();
      s16x8 ah[4], al[4], bh[2], bl[2];
#pragma unroll
      for (int i = 0; i < 4; ++i) {
        ah[i] = *(const s16x8*)(lds + arow[i]);
        al[i] = *(const s16x8*)(lds + 8192 + arow[i]);
      }
#pragma unroll
      for (int j = 0; j < 2; ++j) {
        bh[j] = *(const s16x8*)(lds + brow[j]);
        bl[j] = *(const s16x8*)(lds + 4096 + brow[j]);
      }
#pragma unroll
      for (int i = 0; i < 4; ++i)
#pragma unroll
        for (int j = 0; j < 2; ++j) {
          acc[i][j] = __builtin_amdgcn_mfma_f32_16x16x32_bf16(ah[i], bh[j], acc[i][j], 0, 0, 0);
          acc[i][j] = __builtin_amdgcn_mfma_f32_16x16x32_bf16(ah[i], bl[j], acc[i][j], 0, 0, 0);
          acc[i][j] = __builtin_amdgcn_mfma_f32_16x16x32_bf16(al[i], bh[j], acc[i][j], 0, 0, 0);
        }
    }
  }
  float* pb = pout + (size_t)kb * (4608 * 256);
#pragma unroll
  for (int i = 0; i < 4; ++i)
#pragma unroll
    for (int j = 0; j < 2; ++j) {
      int n = oc0 + wc * 32 + j * 16 + (lane & 15);
#pragma unroll
      for (int qq = 0; qq < 4; ++qq) {
        int m = m0 + wr * 64 + i * 16 + (lane >> 4) * 4 + qq;
        pb[(size_t)m * 256 + n] = acc[i][j][qq];
      }
    }
}

// ---- squash: 3 split-K partials + bias -> psT[b][i*1152+r] (i-major) ----
__global__ __launch_bounds__(256) void k_squash2(const float* __restrict__ pout,
    const float* __restrict__ bias, float* __restrict__ psT, int b0) {
  int b_l = blockIdx.x;
  int t = threadIdx.x;
  __shared__ float buf[9216];
  __shared__ float sq[256];
  __shared__ float sc[32];
  float bv = bias[t];
  for (int s = 0; s < 36; ++s) {
    size_t base = ((size_t)(b_l * 36 + s)) * 256 + t;
    float val = pout[base] + pout[base + 1179648] + pout[base + 2359296] + bv;
    sq[t] = val * val;
    __syncthreads();
    if (t < 32) {
      float ss = 0.f;
#pragma unroll
      for (int i = 0; i < 8; ++i) ss += sq[t + i * 32];
      sc[t] = sqrtf(ss) / (1.f + ss);
    }
    __syncthreads();
    buf[t * 36 + s] = val * sc[t & 31];
    __syncthreads();
  }
  float* dst = psT + (size_t)(b0 + b_l) * 9216;
  for (int i = t; i < 9216; i += 256) dst[i] = buf[i];
}

// ---- fused routing v3: block = (class c, 4 batches); priors in REGISTERS ----
// 768 threads = 12 waves. Thread owns 3 r-nodes (rs, rs+384, rs+768) and one
// 8-wide o-half; priors pri[4][3][8] = 96 VGPR. rw slice (590 KB) read once
// per 4 batches (was per 2) -> rw traffic halved vs round-2/3 route.
__global__ __launch_bounds__(768) void k_route3(const float* __restrict__ psT,
    const float* __restrict__ rw, float* __restrict__ vout) {
  int c = blockIdx.x >> 6;
  int g = blockIdx.x & 63;
  int b0 = g * 4;
  int tid = threadIdx.x;
  int wave = tid >> 6, lane = tid & 63;
  int oh = lane >> 5;                 // o-half: lanes 0-31 -> o 0-7, 32-63 -> o 8-15
  int rs = wave * 32 + (lane & 31);   // 0..383
  __shared__ float lredm[12][4];
  __shared__ float lreds[12][4];
  __shared__ float ored[12][2][4][8];
  __shared__ float osum[4][16];
  __shared__ float vsq[4][16];

  float pri[4][3][8];
  float lgr[4][3];
#pragma unroll
  for (int b = 0; b < 4; ++b)
#pragma unroll
    for (int k = 0; k < 3; ++k) {
      lgr[b][k] = 0.f;
#pragma unroll
      for (int j = 0; j < 8; ++j) pri[b][k][j] = 0.f;
    }
#pragma unroll
  for (int k = 0; k < 3; ++k) {
    int r = rs + k * 384;
    const float* wr_ = &rw[((size_t)c * 1152 + r) * 128 + oh * 8];
    float ps8[4][8];
#pragma unroll
    for (int b = 0; b < 4; ++b)
#pragma unroll
      for (int i = 0; i < 8; ++i)
        ps8[b][i] = psT[(size_t)(b0 + b) * 9216 + i * 1152 + r];
#pragma unroll
    for (int i = 0; i < 8; ++i) {
      float4 w0 = *(const float4*)&wr_[i * 16];
      float4 w1 = *(const float4*)&wr_[i * 16 + 4];
      float w8[8] = {w0.x, w0.y, w0.z, w0.w, w1.x, w1.y, w1.z, w1.w};
#pragma unroll
      for (int b = 0; b < 4; ++b)
#pragma unroll
        for (int j = 0; j < 8; ++j)
          pri[b][k][j] = fmaf(ps8[b][i], w8[j], pri[b][k][j]);
    }
  }

  for (int it = 0; it < 3; ++it) {
    float a[4][8];
    if (it == 0) {
      const float invu = 1.f / 1152.f;
#pragma unroll
      for (int b = 0; b < 4; ++b)
#pragma unroll
        for (int j = 0; j < 8; ++j)
          a[b][j] = (pri[b][0][j] + pri[b][1][j] + pri[b][2][j]) * invu;
    } else {
      float mx[4];
#pragma unroll
      for (int b = 0; b < 4; ++b)
        mx[b] = fmaxf(fmaxf(lgr[b][0], lgr[b][1]), lgr[b][2]);
#pragma unroll
      for (int off = 16; off; off >>= 1)
#pragma unroll
        for (int b = 0; b < 4; ++b) mx[b] = fmaxf(mx[b], __shfl_xor(mx[b], off));
      if (lane == 0) {
#pragma unroll
        for (int b = 0; b < 4; ++b) lredm[wave][b] = mx[b];
      }
      __syncthreads();
#pragma unroll
      for (int b = 0; b < 4; ++b) {
        float m = lredm[0][b];
        for (int w = 1; w < 12; ++w) m = fmaxf(m, lredm[w][b]);
        mx[b] = m;
      }
      float sm[4];
#pragma unroll
      for (int b = 0; b < 4; ++b) {
        float s = 0.f;
#pragma unroll
        for (int k = 0; k < 3; ++k) s += expf(lgr[b][k] - mx[b]);
        sm[b] = s;
      }
#pragma unroll
      for (int off = 16; off; off >>= 1)
#pragma unroll
        for (int b = 0; b < 4; ++b) sm[b] += __shfl_xor(sm[b], off);
      if (lane == 0) {
#pragma unroll
        for (int b = 0; b < 4; ++b) lreds[wave][b] = sm[b];
      }
      __syncthreads();
      float inv[4];
#pragma unroll
      for (int b = 0; b < 4; ++b) {
        float s = 0.f;
        for (int w = 0; w < 12; ++w) s += lreds[w][b];
        inv[b] = 1.f / s;
      }
#pragma unroll
      for (int b = 0; b < 4; ++b)
#pragma unroll
        for (int j = 0; j < 8; ++j) a[b][j] = 0.f;
#pragma unroll
      for (int k = 0; k < 3; ++k)
#pragma unroll
        for (int b = 0; b < 4; ++b) {
          float p = expf(lgr[b][k] - mx[b]) * inv[b];
#pragma unroll
          for (int j = 0; j < 8; ++j) a[b][j] = fmaf(p, pri[b][k][j], a[b][j]);
        }
    }
    // reduce a[b][j] over the 32 r-lanes of this (wave, o-half)
#pragma unroll
    for (int off = 16; off; off >>= 1)
#pragma unroll
      for (int b = 0; b < 4; ++b)
#pragma unroll
        for (int j = 0; j < 8; ++j) a[b][j] += __shfl_xor(a[b][j], off);
    if ((lane & 31) == 0) {
#pragma unroll
      for (int b = 0; b < 4; ++b)
#pragma unroll
        for (int j = 0; j < 8; ++j) ored[wave][oh][b][j] = a[b][j];
    }
    __syncthreads();
    if (tid < 64) {
      int b = tid >> 4, o = tid & 15;
      float s = 0.f;
      for (int w = 0; w < 12; ++w) s += ored[w][o >> 3][b][o & 7];
      osum[b][o] = s;
    }
    __syncthreads();
    if (tid < 4) {
      float sqv = 0.f;
#pragma unroll
      for (int o = 0; o < 16; ++o) sqv += osum[tid][o] * osum[tid][o];
      float sc = sqrtf(sqv) / (1.f + sqv);
#pragma unroll
      for (int o = 0; o < 16; ++o) vsq[tid][o] = osum[tid][o] * sc;
    }
    __syncthreads();
    if (it < 2) {
#pragma unroll
      for (int b = 0; b < 4; ++b) {
        float vh[8];
#pragma unroll
        for (int j = 0; j < 8; ++j) vh[j] = vsq[b][oh * 8 + j];
#pragma unroll
        for (int k = 0; k < 3; ++k) {
          float d = 0.f;
#pragma unroll
          for (int j = 0; j < 8; ++j) d = fmaf(pri[b][k][j], vh[j], d);
          d += __shfl_xor(d, 32);
          lgr[b][k] += d;
        }
      }
      __syncthreads();
    }
  }
  if (tid < 64) {
    int b = tid >> 4, o = tid & 15;
    vout[((size_t)c * BB + (b0 + b)) * 16 + o] = vsq[b][o];
  }
}

// ---- classes + argmax one-hot mask ----
__global__ __launch_bounds__(64) void k_cls(const float* __restrict__ v,
                                            float* __restrict__ classes,
                                            float* __restrict__ masked) {
  int b = blockIdx.x;
  int t = threadIdx.x;
  __shared__ float snrm[10];
  __shared__ int samax;
  float vv[16];
  if (t < 10) {
    float sq = 0.f;
#pragma unroll
    for (int o = 0; o < 16; ++o) {
      float xx = v[(size_t)(t * BB + b) * 16 + o];
      vv[o] = xx;
      sq += xx * xx;
    }
    snrm[t] = sqrtf(sq);
  }
  __syncthreads();
  if (t == 0) {
    int am = 0;
    float bm = snrm[0];
    for (int cc = 1; cc < 10; ++cc)
      if (snrm[cc] > bm) { bm = snrm[cc]; am = cc; }
    samax = am;
  }
  __syncthreads();
  if (t < 10) {
    float mx = snrm[0];
    for (int cc = 1; cc < 10; ++cc) mx = fmaxf(mx, snrm[cc]);
    float sm = 0.f;
    for (int cc = 0; cc < 10; ++cc) sm += expf(snrm[cc] - mx);
    classes[b * 10 + t] = expf(snrm[t] - mx) / sm;
    float keep = (t == samax) ? 1.f : 0.f;
#pragma unroll
    for (int o = 0; o < 16; ++o)
      masked[(size_t)b * 160 + t * 16 + o] = vv[o] * keep;
  }
}

// ---- small FC GEMM ----
template <int ACT>
__global__ __launch_bounds__(256) void k_fc(const float* __restrict__ A,
                                            const float* __restrict__ W,
                                            const float* __restrict__ bias,
                                            float* __restrict__ O, int M, int N,
                                            int K) {
  int n0 = blockIdx.x * 64, m0 = blockIdx.y * 64;
  __shared__ float sa[64][17];
  __shared__ float sb[16][64];
  int tid = threadIdx.x, ty = tid >> 4, tx = tid & 15;
  float acc[4][4] = {};
  for (int k0 = 0; k0 < K; k0 += 16) {
    __syncthreads();
    for (int i = tid; i < 64 * 16; i += 256) {
      int m = i >> 4, k = i & 15;
      sa[m][k] = A[(size_t)(m0 + m) * K + k0 + k];
    }
    for (int i = tid; i < 16 * 64; i += 256) {
      int k = i >> 6, n = i & 63;
      int nn = n0 + n;
      sb[k][n] = (nn < N) ? W[(size_t)(k0 + k) * N + nn] : 0.f;
    }
    __syncthreads();
#pragma unroll
    for (int k = 0; k < 16; ++k) {
      float a0 = sa[ty * 4 + 0][k];
      float a1 = sa[ty * 4 + 1][k];
      float a2 = sa[ty * 4 + 2][k];
      float a3 = sa[ty * 4 + 3][k];
      float4 bv = *(const float4*)&sb[k][tx * 4];
      acc[0][0] += a0 * bv.x; acc[0][1] += a0 * bv.y; acc[0][2] += a0 * bv.z; acc[0][3] += a0 * bv.w;
      acc[1][0] += a1 * bv.x; acc[1][1] += a1 * bv.y; acc[1][2] += a1 * bv.z; acc[1][3] += a1 * bv.w;
      acc[2][0] += a2 * bv.x; acc[2][1] += a2 * bv.y; acc[2][2] += a2 * bv.z; acc[2][3] += a2 * bv.w;
      acc[3][0] += a3 * bv.x; acc[3][1] += a3 * bv.y; acc[3][2] += a3 * bv.z; acc[3][3] += a3 * bv.w;
    }
  }
#pragma unroll
  for (int i = 0; i < 4; ++i) {
    int m = m0 + ty * 4 + i;
#pragma unroll
    for (int j = 0; j < 4; ++j) {
      int n = n0 + tx * 4 + j;
      if (n < N) {
        float xv = acc[i][j] + bias[n];
        if (ACT == 0)
          xv = fmaxf(xv, 0.f);
        else
          xv = 1.f / (1.f + expf(-xv));
        O[(size_t)m * N + n] = xv;
      }
    }
  }
}

extern "C" void kernel_launch(void* const* d_in, const int* in_sizes, int n_in,
                              void* d_out, int out_size, void* d_ws,
                              size_t ws_size, hipStream_t stream) {
  (void)in_sizes; (void)n_in; (void)out_size; (void)ws_size;
  const float* x       = (const float*)d_in[0];
  const float* conv1_w = (const float*)d_in[1];
  const float* conv1_b = (const float*)d_in[2];
  const float* prim_w  = (const float*)d_in[3];
  const float* prim_b  = (const float*)d_in[4];
  const float* route_w = (const float*)d_in[5];
  const float* dec_w1  = (const float*)d_in[6];
  const float* dec_b1  = (const float*)d_in[7];
  const float* dec_w2  = (const float*)d_in[8];
  const float* dec_b2  = (const float*)d_in[9];
  const float* dec_w3  = (const float*)d_in[10];
  const float* dec_b3  = (const float*)d_in[11];
  float* out = (float*)d_out;

  char* wsb = (char*)d_ws;
  __hip_bfloat16* hT_hi = (__hip_bfloat16*)(wsb);                 // 26,214,400 B (half batch)
  __hip_bfloat16* hT_lo = (__hip_bfloat16*)(wsb + 26214400);      // 26,214,400 B
  __hip_bfloat16* wt_hi = (__hip_bfloat16*)(wsb + 52428800);      // 10,616,832 B
  __hip_bfloat16* wt_lo = (__hip_bfloat16*)(wsb + 63045632);      // 10,616,832 B
  float* pout = (float*)(wsb + 73662464);                         // 14,155,776 B (3 partials)
  float* psT  = (float*)(wsb + 87818240);                         //  9,437,184 B
  float* v    = (float*)(wsb + 97255424);
  float* mk   = (float*)(wsb + 97419264);
  float* h1   = (float*)(wsb + 97583104);
  float* h2   = (float*)(wsb + 98107392);

  k_cvtw<<<1024, 256, 0, stream>>>(prim_w, wt_hi, wt_lo);
  for (int hh = 0; hh < 2; ++hh) {
    int b0 = hh * 128;
    k_conv1b<<<512, 256, 0, stream>>>(x, conv1_w, conv1_b, hT_hi, hT_lo, b0);
    k_prim<<<432, 256, 0, stream>>>(hT_hi, hT_lo, wt_hi, wt_lo, pout);
    k_squash2<<<128, 256, 0, stream>>>(pout, prim_b, psT, b0);
  }
  k_route3<<<640, 768, 0, stream>>>(psT, route_w, v);
  k_cls<<<256, 64, 0, stream>>>(v, out, mk);
  k_fc<0><<<dim3(8, 4), 256, 0, stream>>>(mk, dec_w1, dec_b1, h1, 256, 512, 160);
  k_fc<0><<<dim3(16, 4), 256, 0, stream>>>(h1, dec_w2, dec_b2, h2, 256, 1024, 512);
  k_fc<1><<<dim3(13, 4), 256, 0, stream>>>(h2, dec_w3, dec_b3, out + 2560, 256, 784, 1024);
}

// Round 5
// 815.311 us; speedup vs baseline: 1.6905x; 1.6127x over previous
//
#include <hip/hip_runtime.h>
#include <hip/hip_bf16.h>
#include <math.h>

constexpr int BB = 256;
constexpr int NCLS = 10;
constexpr int NROUTE = 1152;

typedef __attribute__((ext_vector_type(8))) short s16x8;
typedef __attribute__((ext_vector_type(4))) float f32x4;

__device__ __forceinline__ void gl16(const void* g, void* l) {
  __builtin_amdgcn_global_load_lds(
      (const __attribute__((address_space(1))) void*)g,
      (__attribute__((address_space(3))) void*)l, 16, 0, 0);
}

// ---- conv1: x[256,1,28,28] -> hT[b_l][y*20+x][oc] bf16 hi/lo (NHWC), relu ----
__global__ __launch_bounds__(256) void k_conv1b(const float* __restrict__ x,
    const float* __restrict__ w, const float* __restrict__ bias,
    __hip_bfloat16* __restrict__ hT_hi, __hip_bfloat16* __restrict__ hT_lo,
    int b0) {
  int b_l = blockIdx.x >> 2, q = blockIdx.x & 3;
  __shared__ float sx[784];
  __shared__ float sw[64 * 81];
  int t = threadIdx.x;
  for (int i = t; i < 784; i += 256) sx[i] = x[(size_t)(b0 + b_l) * 784 + i];
  for (int i = t; i < 5184; i += 256) sw[i] = w[(size_t)q * 5184 + i];
  __syncthreads();
  int oc = q * 64 + (t & 63);
  int wv = t >> 6;
  float wreg[81];
#pragma unroll
  for (int k = 0; k < 81; ++k) wreg[k] = sw[(t & 63) * 81 + k];
  float bv = bias[oc];
  for (int st = wv * 10; st < wv * 10 + 10; ++st) {
    int y = st >> 1, x0 = (st & 1) * 10;
    float acc[10];
#pragma unroll
    for (int i = 0; i < 10; ++i) acc[i] = bv;
#pragma unroll
    for (int ky = 0; ky < 9; ++ky) {
      const float* row = &sx[(y + ky) * 28 + x0];
      float rv[18];
#pragma unroll
      for (int i = 0; i < 18; ++i) rv[i] = row[i];
#pragma unroll
      for (int kx = 0; kx < 9; ++kx) {
        float wgt = wreg[ky * 9 + kx];
#pragma unroll
        for (int xi = 0; xi < 10; ++xi) acc[xi] = fmaf(rv[kx + xi], wgt, acc[xi]);
      }
    }
#pragma unroll
    for (int xi = 0; xi < 10; ++xi) {
      float av = fmaxf(acc[xi], 0.f);
      __hip_bfloat16 hi = __float2bfloat16(av);
      float lo = av - __bfloat162float(hi);
      size_t idx = ((size_t)(b_l * 400 + y * 20 + x0 + xi)) * 256 + oc;
      hT_hi[idx] = hi;
      hT_lo[idx] = __float2bfloat16(lo);
    }
  }
}

// ---- weight convert: prim_w[oc][ic][81] f32 -> wt[tap][oc][ic] bf16 hi/lo ----
__global__ __launch_bounds__(256) void k_cvtw(const float* __restrict__ w,
    __hip_bfloat16* __restrict__ wt_hi, __hip_bfloat16* __restrict__ wt_lo) {
  int oc = blockIdx.x >> 2, icq = blockIdx.x & 3;
  __shared__ float sw[5184];
  int t = threadIdx.x;
  const float* src = w + ((size_t)oc * 256 + icq * 64) * 81;
  for (int i = t; i < 5184; i += 256) sw[i] = src[i];
  __syncthreads();
  for (int i = t; i < 5184; i += 256) {
    int tap = i >> 6, icl = i & 63;
    float v = sw[icl * 81 + tap];
    __hip_bfloat16 hi = __float2bfloat16(v);
    float lo = v - __bfloat162float(hi);
    size_t dst = (size_t)tap * 65536 + (size_t)oc * 256 + icq * 64 + icl;
    wt_hi[dst] = hi;
    wt_lo[dst] = __float2bfloat16(lo);
  }
}

// ---- primary caps conv: implicit GEMM, BM=128 x BN=128, split-K=3 over taps,
//      2-phase double-buffered staging, XCD-grouped block mapping ----
constexpr int PB_BUF = 32768;  // Ah 8K | Al 8K | Bh 8K | Bl 8K

__global__ __launch_bounds__(512, 2) void k_prim3(
    const __hip_bfloat16* __restrict__ hT_hi, const __hip_bfloat16* __restrict__ hT_lo,
    const __hip_bfloat16* __restrict__ wt_hi, const __hip_bfloat16* __restrict__ wt_lo,
    float* __restrict__ pout) {
  __shared__ __align__(16) char lds[2 * PB_BUF];
  // XCD grouping: Mblk m lives on xcd m%8; its 6 (Nblk,kb) blocks co-resident.
  int x = blockIdx.x & 7, g = blockIdx.x >> 3;
  int nM = (x < 4) ? 5 : 4;
  if (g >= nM * 6) return;
  int Mblk = x + (g / 6) * 8;          // 0..35
  int rem = g - (g / 6) * 6;
  int kb = rem % 3, Nblk = rem / 3;
  int m0 = Mblk * 128, oc0 = Nblk * 128;
  int t = threadIdx.x, wv = t >> 6, lane = t & 63;
  int jswz = (t & 3) ^ ((t >> 2) & 3);
  int rA = t >> 2;  // 0..127: A row / B oc-row
  size_t roA;
  {
    int m = m0 + rA;
    int b = m / 36, s = m - b * 36, oy = s / 6, ox = s - oy * 6;
    roA = ((size_t)(b * 400 + oy * 40 + ox * 2)) * 512 + (size_t)(jswz * 16);
  }
  size_t boB = ((size_t)(oc0 + rA)) * 512 + (size_t)(jswz * 16);
  const char* hTh = (const char*)hT_hi;
  const char* hTl = (const char*)hT_lo;
  const char* wth = (const char*)wt_hi;
  const char* wtl = (const char*)wt_lo;

  auto stage = [&](int bufi, int s) {
    int tt = s >> 3, icc = s & 7;
    int tap = kb * 27 + tt;
    int ky = tap / 9, kx = tap - ky * 9;
    size_t offA = (size_t)((ky * 20 + kx) * 512 + icc * 64);
    size_t offB = (size_t)tap * 131072 + (size_t)(icc * 64);
    char* base = lds + bufi * PB_BUF + wv * 1024;
    gl16(hTh + roA + offA, base);
    gl16(hTl + roA + offA, base + 8192);
    gl16(wth + boB + offB, base + 16384);
    gl16(wtl + boB + offB, base + 24576);
  };

  int wr = wv >> 2, wc = wv & 3;
  int lr = lane & 15;
  int swz16 = ((lane >> 4) ^ (lane & 3)) * 16;
  int arow[4], brow[2];
#pragma unroll
  for (int i = 0; i < 4; ++i) arow[i] = (wr * 64 + i * 16 + lr) * 64 + swz16;
#pragma unroll
  for (int j = 0; j < 2; ++j) brow[j] = 16384 + (wc * 32 + j * 16 + lr) * 64 + swz16;

  f32x4 acc[4][2];
#pragma unroll
  for (int i = 0; i < 4; ++i)
#pragma unroll
    for (int j = 0; j < 2; ++j) acc[i][j] = (f32x4){0.f, 0.f, 0.f, 0.f};

  stage(0, 0);
  __syncthreads();
#pragma unroll 1
  for (int s = 0; s < 216; ++s) {
    int cur = s & 1;
    if (s + 1 < 216) stage(cur ^ 1, s + 1);
    const char* Ab = lds + cur * PB_BUF;
    s16x8 ah[4], al[4], bh[2], bl[2];
#pragma unroll
    for (int i = 0; i < 4; ++i) {
      ah[i] = *(const s16x8*)(Ab + arow[i]);
      al[i] = *(const s16x8*)(Ab + 8192 + arow[i]);
    }
#pragma unroll
    for (int j = 0; j < 2; ++j) {
      bh[j] = *(const s16x8*)(Ab + brow[j]);
      bl[j] = *(const s16x8*)(Ab + 8192 + brow[j]);
    }
#pragma unroll
    for (int i = 0; i < 4; ++i)
#pragma unroll
      for (int j = 0; j < 2; ++j) {
        acc[i][j] = __builtin_amdgcn_mfma_f32_16x16x32_bf16(ah[i], bh[j], acc[i][j], 0, 0, 0);
        acc[i][j] = __builtin_amdgcn_mfma_f32_16x16x32_bf16(ah[i], bl[j], acc[i][j], 0, 0, 0);
        acc[i][j] = __builtin_amdgcn_mfma_f32_16x16x32_bf16(al[i], bh[j], acc[i][j], 0, 0, 0);
      }
    __syncthreads();
  }
  float* pb = pout + (size_t)kb * (4608 * 256);
#pragma unroll
  for (int i = 0; i < 4; ++i)
#pragma unroll
    for (int j = 0; j < 2; ++j) {
      int n = oc0 + wc * 32 + j * 16 + lr;
#pragma unroll
      for (int qq = 0; qq < 4; ++qq) {
        int m = m0 + wr * 64 + i * 16 + (lane >> 4) * 4 + qq;
        pb[(size_t)m * 256 + n] = acc[i][j][qq];
      }
    }
}

// ---- squash: 3 split-K partials + bias -> psT[b][i*1152+r] ----
__global__ __launch_bounds__(256) void k_squash2(const float* __restrict__ pout,
    const float* __restrict__ bias, float* __restrict__ psT, int b0) {
  int b_l = blockIdx.x;
  int t = threadIdx.x;
  __shared__ float buf[9216];
  __shared__ float sq[256];
  __shared__ float sc[32];
  float bv = bias[t];
  for (int s = 0; s < 36; ++s) {
    size_t base = ((size_t)(b_l * 36 + s)) * 256 + t;
    float val = pout[base] + pout[base + 1179648] + pout[base + 2359296] + bv;
    sq[t] = val * val;
    __syncthreads();
    if (t < 32) {
      float ss = 0.f;
#pragma unroll
      for (int i = 0; i < 8; ++i) ss += sq[t + i * 32];
      sc[t] = sqrtf(ss) / (1.f + ss);
    }
    __syncthreads();
    buf[t * 36 + s] = val * sc[t & 31];
    __syncthreads();
  }
  float* dst = psT + (size_t)(b0 + b_l) * 9216;
  for (int i = t; i < 9216; i += 256) dst[i] = buf[i];
}

// ---- fused routing v4: block = (class c, 2 batches); priors in registers,
//      pri[2][3][8] = 48 regs -> no spill (launch_bounds cap 170 VGPR) ----
__global__ __launch_bounds__(768, 3) void k_route4(const float* __restrict__ psT,
    const float* __restrict__ rw, float* __restrict__ vout) {
  int c = blockIdx.x >> 7;
  int bp = blockIdx.x & 127;
  int b0 = bp * 2;
  int tid = threadIdx.x;
  int wave = tid >> 6, lane = tid & 63;
  int oh = lane >> 5;
  int rs = wave * 32 + (lane & 31);  // 0..383
  __shared__ float lredm[12][2];
  __shared__ float lreds[12][2];
  __shared__ float ored[12][2][2][8];
  __shared__ float osum[2][16];
  __shared__ float vsq[2][16];

  float pri[2][3][8];
  float lgr[2][3];
#pragma unroll
  for (int b = 0; b < 2; ++b)
#pragma unroll
    for (int k = 0; k < 3; ++k) {
      lgr[b][k] = 0.f;
#pragma unroll
      for (int j = 0; j < 8; ++j) pri[b][k][j] = 0.f;
    }
#pragma unroll
  for (int k = 0; k < 3; ++k) {
    int r = rs + k * 384;
    const float* wr_ = &rw[((size_t)c * 1152 + r) * 128 + oh * 8];
    float ps8[2][8];
#pragma unroll
    for (int b = 0; b < 2; ++b)
#pragma unroll
      for (int i = 0; i < 8; ++i)
        ps8[b][i] = psT[(size_t)(b0 + b) * 9216 + i * 1152 + r];
#pragma unroll
    for (int i = 0; i < 8; ++i) {
      float4 w0 = *(const float4*)&wr_[i * 16];
      float4 w1 = *(const float4*)&wr_[i * 16 + 4];
      float w8[8] = {w0.x, w0.y, w0.z, w0.w, w1.x, w1.y, w1.z, w1.w};
#pragma unroll
      for (int b = 0; b < 2; ++b)
#pragma unroll
        for (int j = 0; j < 8; ++j)
          pri[b][k][j] = fmaf(ps8[b][i], w8[j], pri[b][k][j]);
    }
  }

  for (int it = 0; it < 3; ++it) {
    float a[2][8];
    if (it == 0) {
      const float invu = 1.f / 1152.f;
#pragma unroll
      for (int b = 0; b < 2; ++b)
#pragma unroll
        for (int j = 0; j < 8; ++j)
          a[b][j] = (pri[b][0][j] + pri[b][1][j] + pri[b][2][j]) * invu;
    } else {
      float mx[2];
#pragma unroll
      for (int b = 0; b < 2; ++b)
        mx[b] = fmaxf(fmaxf(lgr[b][0], lgr[b][1]), lgr[b][2]);
#pragma unroll
      for (int off = 16; off; off >>= 1)
#pragma unroll
        for (int b = 0; b < 2; ++b) mx[b] = fmaxf(mx[b], __shfl_xor(mx[b], off));
      if (lane == 0) {
#pragma unroll
        for (int b = 0; b < 2; ++b) lredm[wave][b] = mx[b];
      }
      __syncthreads();
#pragma unroll
      for (int b = 0; b < 2; ++b) {
        float m = lredm[0][b];
        for (int w = 1; w < 12; ++w) m = fmaxf(m, lredm[w][b]);
        mx[b] = m;
      }
      float er[2][3];
      float sm[2];
#pragma unroll
      for (int b = 0; b < 2; ++b) {
        float s = 0.f;
#pragma unroll
        for (int k = 0; k < 3; ++k) {
          er[b][k] = expf(lgr[b][k] - mx[b]);
          s += er[b][k];
        }
        sm[b] = s;
      }
#pragma unroll
      for (int off = 16; off; off >>= 1)
#pragma unroll
        for (int b = 0; b < 2; ++b) sm[b] += __shfl_xor(sm[b], off);
      if (lane == 0) {
#pragma unroll
        for (int b = 0; b < 2; ++b) lreds[wave][b] = sm[b];
      }
      __syncthreads();
      float inv[2];
#pragma unroll
      for (int b = 0; b < 2; ++b) {
        float s = 0.f;
        for (int w = 0; w < 12; ++w) s += lreds[w][b];
        inv[b] = 1.f / s;
      }
#pragma unroll
      for (int b = 0; b < 2; ++b)
#pragma unroll
        for (int j = 0; j < 8; ++j) a[b][j] = 0.f;
#pragma unroll
      for (int k = 0; k < 3; ++k)
#pragma unroll
        for (int b = 0; b < 2; ++b) {
          float p = er[b][k] * inv[b];
#pragma unroll
          for (int j = 0; j < 8; ++j) a[b][j] = fmaf(p, pri[b][k][j], a[b][j]);
        }
    }
#pragma unroll
    for (int off = 16; off; off >>= 1)
#pragma unroll
      for (int b = 0; b < 2; ++b)
#pragma unroll
        for (int j = 0; j < 8; ++j) a[b][j] += __shfl_xor(a[b][j], off);
    if ((lane & 31) == 0) {
#pragma unroll
      for (int b = 0; b < 2; ++b)
#pragma unroll
        for (int j = 0; j < 8; ++j) ored[wave][oh][b][j] = a[b][j];
    }
    __syncthreads();
    if (tid < 32) {
      int b = tid >> 4, o = tid & 15;
      float s = 0.f;
      for (int w = 0; w < 12; ++w) s += ored[w][o >> 3][b][o & 7];
      osum[b][o] = s;
    }
    __syncthreads();
    if (tid < 2) {
      float sqv = 0.f;
#pragma unroll
      for (int o = 0; o < 16; ++o) sqv += osum[tid][o] * osum[tid][o];
      float sc = sqrtf(sqv) / (1.f + sqv);
#pragma unroll
      for (int o = 0; o < 16; ++o) vsq[tid][o] = osum[tid][o] * sc;
    }
    __syncthreads();
    if (it < 2) {
#pragma unroll
      for (int b = 0; b < 2; ++b) {
        float vh[8];
#pragma unroll
        for (int j = 0; j < 8; ++j) vh[j] = vsq[b][oh * 8 + j];
#pragma unroll
        for (int k = 0; k < 3; ++k) {
          float d = 0.f;
#pragma unroll
          for (int j = 0; j < 8; ++j) d = fmaf(pri[b][k][j], vh[j], d);
          d += __shfl_xor(d, 32);
          lgr[b][k] += d;
        }
      }
      __syncthreads();
    }
  }
  if (tid < 32) {
    int b = tid >> 4, o = tid & 15;
    vout[((size_t)c * BB + (b0 + b)) * 16 + o] = vsq[b][o];
  }
}

// ---- classes + argmax; emits am[b] and selected capsule vsel[b][16] ----
__global__ __launch_bounds__(64) void k_cls2(const float* __restrict__ v,
                                             float* __restrict__ classes,
                                             int* __restrict__ am,
                                             float* __restrict__ vsel) {
  int b = blockIdx.x;
  int t = threadIdx.x;
  __shared__ float snrm[10];
  __shared__ int samax;
  if (t < 10) {
    float sq = 0.f;
#pragma unroll
    for (int o = 0; o < 16; ++o) {
      float xx = v[(size_t)(t * BB + b) * 16 + o];
      sq += xx * xx;
    }
    snrm[t] = sqrtf(sq);
  }
  __syncthreads();
  if (t == 0) {
    int amx = 0;
    float bm = snrm[0];
    for (int cc = 1; cc < 10; ++cc)
      if (snrm[cc] > bm) { bm = snrm[cc]; amx = cc; }
    samax = amx;
    am[b] = amx;
  }
  __syncthreads();
  if (t < 10) {
    float mx = snrm[0];
    for (int cc = 1; cc < 10; ++cc) mx = fmaxf(mx, snrm[cc]);
    float sm = 0.f;
    for (int cc = 0; cc < 10; ++cc) sm += expf(snrm[cc] - mx);
    classes[b * 10 + t] = expf(snrm[t] - mx) / sm;
  }
  if (t < 16) vsel[b * 16 + t] = v[((size_t)samax * BB + b) * 16 + t];
}

// ---- fc1 sparse: masked row has only 16 nonzeros (argmax capsule) ----
__global__ __launch_bounds__(512) void k_fc1s(const float* __restrict__ vsel,
    const int* __restrict__ am, const float* __restrict__ w1,
    const float* __restrict__ b1, float* __restrict__ h1) {
  int b = blockIdx.x;
  int n = threadIdx.x;
  __shared__ float sv[16];
  __shared__ int sam;
  if (n < 16) sv[n] = vsel[b * 16 + n];
  if (n == 0) sam = am[b];
  __syncthreads();
  float acc = b1[n];
  int base = sam * 16;
#pragma unroll
  for (int i = 0; i < 16; ++i)
    acc = fmaf(sv[i], w1[(size_t)(base + i) * 512 + n], acc);
  h1[(size_t)b * 512 + n] = fmaxf(acc, 0.f);
}

// ---- fc 32x32-tile GEMM: O[M,N] = act(A[M,K] @ W[K,N] + bias) ----
template <int ACT>  // 0 = relu, 1 = sigmoid
__global__ __launch_bounds__(256) void k_fc32(const float* __restrict__ A,
                                              const float* __restrict__ W,
                                              const float* __restrict__ bias,
                                              float* __restrict__ O, int M,
                                              int N, int K) {
  int n0 = blockIdx.x * 32, m0 = blockIdx.y * 32;
  __shared__ float sa[32][33];
  __shared__ float sb[32][34];
  int tid = threadIdx.x, ty = tid >> 4, tx = tid & 15;
  float acc[2][2] = {};
  for (int k0 = 0; k0 < K; k0 += 32) {
    __syncthreads();
    for (int i = tid; i < 1024; i += 256) {
      int m = i >> 5, k = i & 31;
      sa[m][k] = A[(size_t)(m0 + m) * K + k0 + k];
      int kk = i >> 5, n = i & 31;
      int nn = n0 + n;
      sb[kk][n] = (nn < N) ? W[(size_t)(k0 + kk) * N + nn] : 0.f;
    }
    __syncthreads();
#pragma unroll
    for (int k = 0; k < 32; ++k) {
      float a0 = sa[ty * 2 + 0][k];
      float a1 = sa[ty * 2 + 1][k];
      float b0 = sb[k][tx * 2 + 0];
      float b1v = sb[k][tx * 2 + 1];
      acc[0][0] = fmaf(a0, b0, acc[0][0]);
      acc[0][1] = fmaf(a0, b1v, acc[0][1]);
      acc[1][0] = fmaf(a1, b0, acc[1][0]);
      acc[1][1] = fmaf(a1, b1v, acc[1][1]);
    }
  }
#pragma unroll
  for (int i = 0; i < 2; ++i) {
    int m = m0 + ty * 2 + i;
#pragma unroll
    for (int j = 0; j < 2; ++j) {
      int n = n0 + tx * 2 + j;
      if (n < N) {
        float xv = acc[i][j] + bias[n];
        if (ACT == 0)
          xv = fmaxf(xv, 0.f);
        else
          xv = 1.f / (1.f + expf(-xv));
        O[(size_t)m * N + n] = xv;
      }
    }
  }
}

extern "C" void kernel_launch(void* const* d_in, const int* in_sizes, int n_in,
                              void* d_out, int out_size, void* d_ws,
                              size_t ws_size, hipStream_t stream) {
  (void)in_sizes; (void)n_in; (void)out_size; (void)ws_size;
  const float* x       = (const float*)d_in[0];
  const float* conv1_w = (const float*)d_in[1];
  const float* conv1_b = (const float*)d_in[2];
  const float* prim_w  = (const float*)d_in[3];
  const float* prim_b  = (const float*)d_in[4];
  const float* route_w = (const float*)d_in[5];
  const float* dec_w1  = (const float*)d_in[6];
  const float* dec_b1  = (const float*)d_in[7];
  const float* dec_w2  = (const float*)d_in[8];
  const float* dec_b2  = (const float*)d_in[9];
  const float* dec_w3  = (const float*)d_in[10];
  const float* dec_b3  = (const float*)d_in[11];
  float* out = (float*)d_out;

  char* wsb = (char*)d_ws;
  __hip_bfloat16* hT_hi = (__hip_bfloat16*)(wsb);                 // 26,214,400 B
  __hip_bfloat16* hT_lo = (__hip_bfloat16*)(wsb + 26214400);      // 26,214,400 B
  __hip_bfloat16* wt_hi = (__hip_bfloat16*)(wsb + 52428800);      // 10,616,832 B
  __hip_bfloat16* wt_lo = (__hip_bfloat16*)(wsb + 63045632);      // 10,616,832 B
  float* pout = (float*)(wsb + 73662464);                         // 14,155,776 B
  float* psT  = (float*)(wsb + 87818240);                         //  9,437,184 B
  float* v    = (float*)(wsb + 97255424);                         //   163,840 B
  float* h1   = (float*)(wsb + 97419264);                         //   524,288 B
  float* h2   = (float*)(wsb + 97943552);                         // 1,048,576 B
  int*   am   = (int*)  (wsb + 98992128);                         //     4,096 B
  float* vsel = (float*)(wsb + 98996224);                         //    16,384 B

  k_cvtw<<<1024, 256, 0, stream>>>(prim_w, wt_hi, wt_lo);
  for (int hh = 0; hh < 2; ++hh) {
    int b0 = hh * 128;
    k_conv1b<<<512, 256, 0, stream>>>(x, conv1_w, conv1_b, hT_hi, hT_lo, b0);
    k_prim3<<<240, 512, 0, stream>>>(hT_hi, hT_lo, wt_hi, wt_lo, pout);
    k_squash2<<<128, 256, 0, stream>>>(pout, prim_b, psT, b0);
  }
  k_route4<<<1280, 768, 0, stream>>>(psT, route_w, v);
  k_cls2<<<256, 64, 0, stream>>>(v, out, am, vsel);
  k_fc1s<<<256, 512, 0, stream>>>(vsel, am, dec_w1, dec_b1, h1);
  k_fc32<0><<<dim3(32, 8), 256, 0, stream>>>(h1, dec_w2, dec_b2, h2, 256, 1024, 512);
  k_fc32<1><<<dim3(25, 8), 256, 0, stream>>>(h2, dec_w3, dec_b3, out + 2560, 256, 784, 1024);
}

// Round 6
// 792.640 us; speedup vs baseline: 1.7388x; 1.0286x over previous
//
#include <hip/hip_runtime.h>
#include <hip/hip_bf16.h>
#include <math.h>

constexpr int BB = 256;
constexpr int NCLS = 10;
constexpr int NROUTE = 1152;

typedef __attribute__((ext_vector_type(8))) short s16x8;
typedef __attribute__((ext_vector_type(4))) float f32x4;

__device__ __forceinline__ void gl16(const void* g, void* l) {
  __builtin_amdgcn_global_load_lds(
      (const __attribute__((address_space(1))) void*)g,
      (__attribute__((address_space(3))) void*)l, 16, 0, 0);
}

// ---- conv1: x[256,1,28,28] -> hT[b_l][y*20+x][oc] bf16 hi/lo (NHWC), relu ----
__global__ __launch_bounds__(256) void k_conv1b(const float* __restrict__ x,
    const float* __restrict__ w, const float* __restrict__ bias,
    __hip_bfloat16* __restrict__ hT_hi, __hip_bfloat16* __restrict__ hT_lo,
    int b0) {
  int b_l = blockIdx.x >> 2, q = blockIdx.x & 3;
  __shared__ float sx[784];
  __shared__ float sw[64 * 81];
  int t = threadIdx.x;
  for (int i = t; i < 784; i += 256) sx[i] = x[(size_t)(b0 + b_l) * 784 + i];
  for (int i = t; i < 5184; i += 256) sw[i] = w[(size_t)q * 5184 + i];
  __syncthreads();
  int oc = q * 64 + (t & 63);
  int wv = t >> 6;
  float wreg[81];
#pragma unroll
  for (int k = 0; k < 81; ++k) wreg[k] = sw[(t & 63) * 81 + k];
  float bv = bias[oc];
  for (int st = wv * 10; st < wv * 10 + 10; ++st) {
    int y = st >> 1, x0 = (st & 1) * 10;
    float acc[10];
#pragma unroll
    for (int i = 0; i < 10; ++i) acc[i] = bv;
#pragma unroll
    for (int ky = 0; ky < 9; ++ky) {
      const float* row = &sx[(y + ky) * 28 + x0];
      float rv[18];
#pragma unroll
      for (int i = 0; i < 18; ++i) rv[i] = row[i];
#pragma unroll
      for (int kx = 0; kx < 9; ++kx) {
        float wgt = wreg[ky * 9 + kx];
#pragma unroll
        for (int xi = 0; xi < 10; ++xi) acc[xi] = fmaf(rv[kx + xi], wgt, acc[xi]);
      }
    }
#pragma unroll
    for (int xi = 0; xi < 10; ++xi) {
      float av = fmaxf(acc[xi], 0.f);
      __hip_bfloat16 hi = __float2bfloat16(av);
      float lo = av - __bfloat162float(hi);
      size_t idx = ((size_t)(b_l * 400 + y * 20 + x0 + xi)) * 256 + oc;
      hT_hi[idx] = hi;
      hT_lo[idx] = __float2bfloat16(lo);
    }
  }
}

// ---- weight convert: prim_w[oc][ic][81] f32 -> wt[tap][oc][ic] bf16 hi/lo ----
__global__ __launch_bounds__(256) void k_cvtw(const float* __restrict__ w,
    __hip_bfloat16* __restrict__ wt_hi, __hip_bfloat16* __restrict__ wt_lo) {
  int oc = blockIdx.x >> 2, icq = blockIdx.x & 3;
  __shared__ float sw[5184];
  int t = threadIdx.x;
  const float* src = w + ((size_t)oc * 256 + icq * 64) * 81;
  for (int i = t; i < 5184; i += 256) sw[i] = src[i];
  __syncthreads();
  for (int i = t; i < 5184; i += 256) {
    int tap = i >> 6, icl = i & 63;
    float v = sw[icl * 81 + tap];
    __hip_bfloat16 hi = __float2bfloat16(v);
    float lo = v - __bfloat162float(hi);
    size_t dst = (size_t)tap * 65536 + (size_t)oc * 256 + icq * 64 + icl;
    wt_hi[dst] = hi;
    wt_lo[dst] = __float2bfloat16(lo);
  }
}

// ---- primary caps conv: implicit GEMM, BM=128 x BN=128, split-K=3 over taps,
//      2-phase double-buffered staging, XCD-grouped block mapping ----
constexpr int PB_BUF = 32768;  // Ah 8K | Al 8K | Bh 8K | Bl 8K

__global__ __launch_bounds__(512, 2) void k_prim3(
    const __hip_bfloat16* __restrict__ hT_hi, const __hip_bfloat16* __restrict__ hT_lo,
    const __hip_bfloat16* __restrict__ wt_hi, const __hip_bfloat16* __restrict__ wt_lo,
    float* __restrict__ pout) {
  __shared__ __align__(16) char lds[2 * PB_BUF];
  int x = blockIdx.x & 7, g = blockIdx.x >> 3;
  int nM = (x < 4) ? 5 : 4;
  if (g >= nM * 6) return;
  int Mblk = x + (g / 6) * 8;          // 0..35
  int rem = g - (g / 6) * 6;
  int kb = rem % 3, Nblk = rem / 3;
  int m0 = Mblk * 128, oc0 = Nblk * 128;
  int t = threadIdx.x, wv = t >> 6, lane = t & 63;
  int jswz = (t & 3) ^ ((t >> 2) & 3);
  int rA = t >> 2;  // 0..127
  size_t roA;
  {
    int m = m0 + rA;
    int b = m / 36, s = m - b * 36, oy = s / 6, ox = s - oy * 6;
    roA = ((size_t)(b * 400 + oy * 40 + ox * 2)) * 512 + (size_t)(jswz * 16);
  }
  size_t boB = ((size_t)(oc0 + rA)) * 512 + (size_t)(jswz * 16);
  const char* hTh = (const char*)hT_hi;
  const char* hTl = (const char*)hT_lo;
  const char* wth = (const char*)wt_hi;
  const char* wtl = (const char*)wt_lo;

  auto stage = [&](int bufi, int s) {
    int tt = s >> 3, icc = s & 7;
    int tap = kb * 27 + tt;
    int ky = tap / 9, kx = tap - ky * 9;
    size_t offA = (size_t)((ky * 20 + kx) * 512 + icc * 64);
    size_t offB = (size_t)tap * 131072 + (size_t)(icc * 64);
    char* base = lds + bufi * PB_BUF + wv * 1024;
    gl16(hTh + roA + offA, base);
    gl16(hTl + roA + offA, base + 8192);
    gl16(wth + boB + offB, base + 16384);
    gl16(wtl + boB + offB, base + 24576);
  };

  int wr = wv >> 2, wc = wv & 3;
  int lr = lane & 15;
  int swz16 = ((lane >> 4) ^ (lane & 3)) * 16;
  int arow[4], brow[2];
#pragma unroll
  for (int i = 0; i < 4; ++i) arow[i] = (wr * 64 + i * 16 + lr) * 64 + swz16;
#pragma unroll
  for (int j = 0; j < 2; ++j) brow[j] = 16384 + (wc * 32 + j * 16 + lr) * 64 + swz16;

  f32x4 acc[4][2];
#pragma unroll
  for (int i = 0; i < 4; ++i)
#pragma unroll
    for (int j = 0; j < 2; ++j) acc[i][j] = (f32x4){0.f, 0.f, 0.f, 0.f};

  stage(0, 0);
  __syncthreads();
#pragma unroll 1
  for (int s = 0; s < 216; ++s) {
    int cur = s & 1;
    if (s + 1 < 216) stage(cur ^ 1, s + 1);
    const char* Ab = lds + cur * PB_BUF;
    s16x8 ah[4], al[4], bh[2], bl[2];
#pragma unroll
    for (int i = 0; i < 4; ++i) {
      ah[i] = *(const s16x8*)(Ab + arow[i]);
      al[i] = *(const s16x8*)(Ab + 8192 + arow[i]);
    }
#pragma unroll
    for (int j = 0; j < 2; ++j) {
      bh[j] = *(const s16x8*)(Ab + brow[j]);
      bl[j] = *(const s16x8*)(Ab + 8192 + brow[j]);
    }
#pragma unroll
    for (int i = 0; i < 4; ++i)
#pragma unroll
      for (int j = 0; j < 2; ++j) {
        acc[i][j] = __builtin_amdgcn_mfma_f32_16x16x32_bf16(ah[i], bh[j], acc[i][j], 0, 0, 0);
        acc[i][j] = __builtin_amdgcn_mfma_f32_16x16x32_bf16(ah[i], bl[j], acc[i][j], 0, 0, 0);
        acc[i][j] = __builtin_amdgcn_mfma_f32_16x16x32_bf16(al[i], bh[j], acc[i][j], 0, 0, 0);
      }
    __syncthreads();
  }
  float* pb = pout + (size_t)kb * (4608 * 256);
#pragma unroll
  for (int i = 0; i < 4; ++i)
#pragma unroll
    for (int j = 0; j < 2; ++j) {
      int n = oc0 + wc * 32 + j * 16 + lr;
#pragma unroll
      for (int qq = 0; qq < 4; ++qq) {
        int m = m0 + wr * 64 + i * 16 + (lane >> 4) * 4 + qq;
        pb[(size_t)m * 256 + n] = acc[i][j][qq];
      }
    }
}

// ---- squash: 3 split-K partials + bias -> psT[b][i*1152+r] ----
__global__ __launch_bounds__(256) void k_squash2(const float* __restrict__ pout,
    const float* __restrict__ bias, float* __restrict__ psT, int b0) {
  int b_l = blockIdx.x;
  int t = threadIdx.x;
  __shared__ float buf[9216];
  __shared__ float sq[256];
  __shared__ float sc[32];
  float bv = bias[t];
  for (int s = 0; s < 36; ++s) {
    size_t base = ((size_t)(b_l * 36 + s)) * 256 + t;
    float val = pout[base] + pout[base + 1179648] + pout[base + 2359296] + bv;
    sq[t] = val * val;
    __syncthreads();
    if (t < 32) {
      float ss = 0.f;
#pragma unroll
      for (int i = 0; i < 8; ++i) ss += sq[t + i * 32];
      sc[t] = sqrtf(ss) / (1.f + ss);
    }
    __syncthreads();
    buf[t * 36 + s] = val * sc[t & 31];
    __syncthreads();
  }
  float* dst = psT + (size_t)(b0 + b_l) * 9216;
  for (int i = t; i < 9216; i += 256) dst[i] = buf[i];
}

// ---- fused routing v5: block = (class c, ONE batch); priors in registers.
//      Per-thread live set ~55 regs -> fits the compiler's 84-VGPR budget, NO spill.
//      768 threads = 12 waves; thread owns 3 r-nodes x 8-wide o-half. ----
__global__ __launch_bounds__(768) void k_route5(const float* __restrict__ psT,
    const float* __restrict__ rw, float* __restrict__ vout) {
  int c = blockIdx.x >> 8;          // class-major: same-c blocks co-scheduled
  int b = blockIdx.x & 255;
  int tid = threadIdx.x;
  int wave = tid >> 6, lane = tid & 63;
  int oh = lane >> 5;               // lanes 0-31: o 0-7, lanes 32-63: o 8-15
  int rs = wave * 32 + (lane & 31); // 0..383; r = rs + k*384
  __shared__ float lredm[12];
  __shared__ float lreds[12];
  __shared__ float ored[12][2][8];
  __shared__ float osum[16];
  __shared__ float vsq[16];

  float pri[3][8];
  float lgr[3] = {0.f, 0.f, 0.f};
#pragma unroll
  for (int k = 0; k < 3; ++k)
#pragma unroll
    for (int j = 0; j < 8; ++j) pri[k][j] = 0.f;

#pragma unroll
  for (int k = 0; k < 3; ++k) {
    int r = rs + k * 384;
    const float* wr_ = &rw[((size_t)c * 1152 + r) * 128 + oh * 8];
    float ps8[8];
#pragma unroll
    for (int i = 0; i < 8; ++i) ps8[i] = psT[(size_t)b * 9216 + i * 1152 + r];
#pragma unroll
    for (int i = 0; i < 8; ++i) {
      float4 w0 = *(const float4*)&wr_[i * 16];
      float4 w1 = *(const float4*)&wr_[i * 16 + 4];
      float w8[8] = {w0.x, w0.y, w0.z, w0.w, w1.x, w1.y, w1.z, w1.w};
#pragma unroll
      for (int j = 0; j < 8; ++j) pri[k][j] = fmaf(ps8[i], w8[j], pri[k][j]);
    }
  }

  for (int it = 0; it < 3; ++it) {
    float a[8];
    if (it == 0) {
      const float invu = 1.f / 1152.f;
#pragma unroll
      for (int j = 0; j < 8; ++j)
        a[j] = (pri[0][j] + pri[1][j] + pri[2][j]) * invu;
    } else {
      float mx = fmaxf(fmaxf(lgr[0], lgr[1]), lgr[2]);
#pragma unroll
      for (int off = 16; off; off >>= 1) mx = fmaxf(mx, __shfl_xor(mx, off));
      if (lane == 0) lredm[wave] = mx;
      __syncthreads();
      mx = lredm[0];
      for (int w = 1; w < 12; ++w) mx = fmaxf(mx, lredm[w]);
      float er[3];
      float sm = 0.f;
#pragma unroll
      for (int k = 0; k < 3; ++k) {
        er[k] = expf(lgr[k] - mx);
        sm += er[k];
      }
#pragma unroll
      for (int off = 16; off; off >>= 1) sm += __shfl_xor(sm, off);
      if (lane == 0) lreds[wave] = sm;
      __syncthreads();
      float s = 0.f;
      for (int w = 0; w < 12; ++w) s += lreds[w];
      float inv = 1.f / s;
#pragma unroll
      for (int j = 0; j < 8; ++j) a[j] = 0.f;
#pragma unroll
      for (int k = 0; k < 3; ++k) {
        float p = er[k] * inv;
#pragma unroll
        for (int j = 0; j < 8; ++j) a[j] = fmaf(p, pri[k][j], a[j]);
      }
    }
    // reduce over the 32 r-lanes of this (wave, o-half)
#pragma unroll
    for (int off = 16; off; off >>= 1)
#pragma unroll
      for (int j = 0; j < 8; ++j) a[j] += __shfl_xor(a[j], off);
    if ((lane & 31) == 0) {
#pragma unroll
      for (int j = 0; j < 8; ++j) ored[wave][oh][j] = a[j];
    }
    __syncthreads();
    if (tid < 16) {
      float s = 0.f;
      for (int w = 0; w < 12; ++w) s += ored[w][tid >> 3][tid & 7];
      osum[tid] = s;
    }
    __syncthreads();
    if (tid < 16) {
      float sqv = 0.f;
#pragma unroll
      for (int o = 0; o < 16; ++o) sqv += osum[o] * osum[o];
      float sc = sqrtf(sqv) / (1.f + sqv);
      vsq[tid] = osum[tid] * sc;
    }
    __syncthreads();
    if (it < 2) {
      float vh[8];
#pragma unroll
      for (int j = 0; j < 8; ++j) vh[j] = vsq[oh * 8 + j];
#pragma unroll
      for (int k = 0; k < 3; ++k) {
        float d = 0.f;
#pragma unroll
        for (int j = 0; j < 8; ++j) d = fmaf(pri[k][j], vh[j], d);
        d += __shfl_xor(d, 32);
        lgr[k] += d;
      }
      __syncthreads();
    }
  }
  if (tid < 16) vout[((size_t)c * BB + b) * 16 + tid] = vsq[tid];
}

// ---- classes + argmax; emits am[b] and selected capsule vsel[b][16] ----
__global__ __launch_bounds__(64) void k_cls2(const float* __restrict__ v,
                                             float* __restrict__ classes,
                                             int* __restrict__ am,
                                             float* __restrict__ vsel) {
  int b = blockIdx.x;
  int t = threadIdx.x;
  __shared__ float snrm[10];
  __shared__ int samax;
  if (t < 10) {
    float sq = 0.f;
#pragma unroll
    for (int o = 0; o < 16; ++o) {
      float xx = v[(size_t)(t * BB + b) * 16 + o];
      sq += xx * xx;
    }
    snrm[t] = sqrtf(sq);
  }
  __syncthreads();
  if (t == 0) {
    int amx = 0;
    float bm = snrm[0];
    for (int cc = 1; cc < 10; ++cc)
      if (snrm[cc] > bm) { bm = snrm[cc]; amx = cc; }
    samax = amx;
    am[b] = amx;
  }
  __syncthreads();
  if (t < 10) {
    float mx = snrm[0];
    for (int cc = 1; cc < 10; ++cc) mx = fmaxf(mx, snrm[cc]);
    float sm = 0.f;
    for (int cc = 0; cc < 10; ++cc) sm += expf(snrm[cc] - mx);
    classes[b * 10 + t] = expf(snrm[t] - mx) / sm;
  }
  if (t < 16) vsel[b * 16 + t] = v[((size_t)samax * BB + b) * 16 + t];
}

// ---- fc1 sparse: masked row has only 16 nonzeros (argmax capsule) ----
__global__ __launch_bounds__(512) void k_fc1s(const float* __restrict__ vsel,
    const int* __restrict__ am, const float* __restrict__ w1,
    const float* __restrict__ b1, float* __restrict__ h1) {
  int b = blockIdx.x;
  int n = threadIdx.x;
  __shared__ float sv[16];
  __shared__ int sam;
  if (n < 16) sv[n] = vsel[b * 16 + n];
  if (n == 0) sam = am[b];
  __syncthreads();
  float acc = b1[n];
  int base = sam * 16;
#pragma unroll
  for (int i = 0; i < 16; ++i)
    acc = fmaf(sv[i], w1[(size_t)(base + i) * 512 + n], acc);
  h1[(size_t)b * 512 + n] = fmaxf(acc, 0.f);
}

// ---- fc 32x32-tile GEMM: O[M,N] = act(A[M,K] @ W[K,N] + bias) ----
template <int ACT>  // 0 = relu, 1 = sigmoid
__global__ __launch_bounds__(256) void k_fc32(const float* __restrict__ A,
                                              const float* __restrict__ W,
                                              const float* __restrict__ bias,
                                              float* __restrict__ O, int M,
                                              int N, int K) {
  int n0 = blockIdx.x * 32, m0 = blockIdx.y * 32;
  __shared__ float sa[32][33];
  __shared__ float sb[32][34];
  int tid = threadIdx.x, ty = tid >> 4, tx = tid & 15;
  float acc[2][2] = {};
  for (int k0 = 0; k0 < K; k0 += 32) {
    __syncthreads();
    for (int i = tid; i < 1024; i += 256) {
      int m = i >> 5, k = i & 31;
      sa[m][k] = A[(size_t)(m0 + m) * K + k0 + k];
      int kk = i >> 5, n = i & 31;
      int nn = n0 + n;
      sb[kk][n] = (nn < N) ? W[(size_t)(k0 + kk) * N + nn] : 0.f;
    }
    __syncthreads();
#pragma unroll
    for (int k = 0; k < 32; ++k) {
      float a0 = sa[ty * 2 + 0][k];
      float a1 = sa[ty * 2 + 1][k];
      float b0 = sb[k][tx * 2 + 0];
      float b1v = sb[k][tx * 2 + 1];
      acc[0][0] = fmaf(a0, b0, acc[0][0]);
      acc[0][1] = fmaf(a0, b1v, acc[0][1]);
      acc[1][0] = fmaf(a1, b0, acc[1][0]);
      acc[1][1] = fmaf(a1, b1v, acc[1][1]);
    }
  }
#pragma unroll
  for (int i = 0; i < 2; ++i) {
    int m = m0 + ty * 2 + i;
#pragma unroll
    for (int j = 0; j < 2; ++j) {
      int n = n0 + tx * 2 + j;
      if (n < N) {
        float xv = acc[i][j] + bias[n];
        if (ACT == 0)
          xv = fmaxf(xv, 0.f);
        else
          xv = 1.f / (1.f + expf(-xv));
        O[(size_t)m * N + n] = xv;
      }
    }
  }
}

extern "C" void kernel_launch(void* const* d_in, const int* in_sizes, int n_in,
                              void* d_out, int out_size, void* d_ws,
                              size_t ws_size, hipStream_t stream) {
  (void)in_sizes; (void)n_in; (void)out_size; (void)ws_size;
  const float* x       = (const float*)d_in[0];
  const float* conv1_w = (const float*)d_in[1];
  const float* conv1_b = (const float*)d_in[2];
  const float* prim_w  = (const float*)d_in[3];
  const float* prim_b  = (const float*)d_in[4];
  const float* route_w = (const float*)d_in[5];
  const float* dec_w1  = (const float*)d_in[6];
  const float* dec_b1  = (const float*)d_in[7];
  const float* dec_w2  = (const float*)d_in[8];
  const float* dec_b2  = (const float*)d_in[9];
  const float* dec_w3  = (const float*)d_in[10];
  const float* dec_b3  = (const float*)d_in[11];
  float* out = (float*)d_out;

  char* wsb = (char*)d_ws;
  __hip_bfloat16* hT_hi = (__hip_bfloat16*)(wsb);                 // 26,214,400 B
  __hip_bfloat16* hT_lo = (__hip_bfloat16*)(wsb + 26214400);      // 26,214,400 B
  __hip_bfloat16* wt_hi = (__hip_bfloat16*)(wsb + 52428800);      // 10,616,832 B
  __hip_bfloat16* wt_lo = (__hip_bfloat16*)(wsb + 63045632);      // 10,616,832 B
  float* pout = (float*)(wsb + 73662464);                         // 14,155,776 B
  float* psT  = (float*)(wsb + 87818240);                         //  9,437,184 B
  float* v    = (float*)(wsb + 97255424);                         //   163,840 B
  float* h1   = (float*)(wsb + 97419264);                         //   524,288 B
  float* h2   = (float*)(wsb + 97943552);                         // 1,048,576 B
  int*   am   = (int*)  (wsb + 98992128);                         //     4,096 B
  float* vsel = (float*)(wsb + 98996224);                         //    16,384 B

  k_cvtw<<<1024, 256, 0, stream>>>(prim_w, wt_hi, wt_lo);
  for (int hh = 0; hh < 2; ++hh) {
    int b0 = hh * 128;
    k_conv1b<<<512, 256, 0, stream>>>(x, conv1_w, conv1_b, hT_hi, hT_lo, b0);
    k_prim3<<<240, 512, 0, stream>>>(hT_hi, hT_lo, wt_hi, wt_lo, pout);
    k_squash2<<<128, 256, 0, stream>>>(pout, prim_b, psT, b0);
  }
  k_route5<<<2560, 768, 0, stream>>>(psT, route_w, v);
  k_cls2<<<256, 64, 0, stream>>>(v, out, am, vsel);
  k_fc1s<<<256, 512, 0, stream>>>(vsel, am, dec_w1, dec_b1, h1);
  k_fc32<0><<<dim3(32, 8), 256, 0, stream>>>(h1, dec_w2, dec_b2, h2, 256, 1024, 512);
  k_fc32<1><<<dim3(25, 8), 256, 0, stream>>>(h2, dec_w3, dec_b3, out + 2560, 256, 784, 1024);
}